// Round 8
// baseline (18683.694 us; speedup 1.0000x reference)
//
#include <hip/hip_runtime.h>

// ODE-GRU on MI355X, round 8.
// Structure = round 7 (512x512, pair-split f16 dot2, 8-way drift stage1,
// single dopri5 step, f16 GRU weights streamed from d_ws). Changes:
//  1. All cross-lane reductions via DPP v_add (quad_perm 0xB1/0x4E +
//     row_half_mirror 0x141) instead of __shfl_xor's LDS round-trips.
//  2. tanh computed by all lanes (only the uh ds_write is masked).
//  3. GRU hh loop: explicit depth-2 software-pipelined WHx prefetch;
//     ih loads batched before their dots.
//  4. yA/yB ping-pong drift buffers -> GRU-end + bottom barriers removed
//     (13 barriers/step instead of 15; WAR gaps span >=1 barrier).

#define SEQ   256
#define BATCH 512
#define DIN   54
#define HDIM  256
#define DH    64

typedef _Float16 h2 __attribute__((ext_vector_type(2)));
typedef _Float16 h8 __attribute__((ext_vector_type(8)));

#define PX(v, p) __builtin_shufflevector((v), (v), 2*(p), 2*(p)+1)

#if defined(__has_builtin)
#  if __has_builtin(__builtin_amdgcn_fdot2)
#    define FDOT2(a, b, c) __builtin_amdgcn_fdot2((a), (b), (c), false)
#  endif
#endif
#ifndef FDOT2
#  define FDOT2(a, b, c) fmaf((float)(a)[0], (float)(b)[0], \
                         fmaf((float)(a)[1], (float)(b)[1], (c)))
#endif

__device__ __forceinline__ float rcp_f(float x) { return __builtin_amdgcn_rcpf(x); }

__device__ __forceinline__ float fast_tanh(float x) {
    x = fminf(15.0f, fmaxf(-15.0f, x));
    float e = __expf(2.0f * x);
    return 1.0f - 2.0f * rcp_f(e + 1.0f);
}
__device__ __forceinline__ float fast_sigmoid(float x) {
    x = fminf(30.0f, fmaxf(-30.0f, x));
    return rcp_f(1.0f + __expf(-x));
}

// x + dpp_permute(x): cross-lane add at VALU latency (no LDS).
// 0xB1 = quad_perm [1,0,3,2] (lane^1). 0x4E = quad_perm [2,3,0,1] (lane^2).
// 0x141 = row_half_mirror (lane^7 within 8) -- valid for the 8-lane sum
// because after xor1+xor2 the value is quad-uniform, and ^7 lands in the
// opposite quad of the same 8-lane group.
template <int CTRL>
__device__ __forceinline__ float dppadd(float x) {
    return x + __int_as_float(
        __builtin_amdgcn_mov_dpp(__float_as_int(x), CTRL, 0xF, 0xF, true));
}

// 4 dot2: accumulate h8 W . h8 Y into A
#define DOT8(A, W, Y) { \
    A = FDOT2(PX(W,0), PX(Y,0), A); A = FDOT2(PX(W,1), PX(Y,1), A); \
    A = FDOT2(PX(W,2), PX(Y,2), A); A = FDOT2(PX(W,3), PX(Y,3), A); }

// Drift eval into/out of buffer YB (ping-pong between calls removes WAR
// barriers). Stage1: 8-lane group (i1=t>>3) over interleaved k-chunks
// (conflict-free LDS); DPP xor1/xor2/^7 completes the 256-dot. Stage2:
// pair halves over uh broadcast; DPP xor1 completes. 2 barriers (RAW only).
#define DRIFT(YB, Y_EXPR, KOUT) do {                                          \
    if (p == 0) YB[j] = (_Float16)(Y_EXPR);                                   \
    __syncthreads();                                                          \
    float a0_ = 0.f, a1_ = 0.f, a2_ = 0.f, a3_ = 0.f;                         \
    {                                                                         \
        h8 v0_ = *(const h8*)(YB + k8 * 8 +   0);                             \
        h8 v1_ = *(const h8*)(YB + k8 * 8 +  64);                             \
        h8 v2_ = *(const h8*)(YB + k8 * 8 + 128);                             \
        h8 v3_ = *(const h8*)(YB + k8 * 8 + 192);                             \
        DOT8(a0_, w1m0, v0_) DOT8(a1_, w1m1, v1_)                             \
        DOT8(a2_, w1m2, v2_) DOT8(a3_, w1m3, v3_)                             \
    }                                                                         \
    float as_ = (a0_ + a1_) + (a2_ + a3_);                                    \
    as_ = dppadd<0xB1>(as_);                                                  \
    as_ = dppadd<0x4E>(as_);                                                  \
    as_ = dppadd<0x141>(as_);                                                 \
    float uu_ = fast_tanh(as_ + b1r);                                         \
    if (k8 == 0) uh[i1] = (_Float16)uu_;                                      \
    __syncthreads();                                                          \
    float c0_ = 0.f, c1_ = 0.f, c2_ = 0.f, c3_ = 0.f;                         \
    {                                                                         \
        h8 u0_ = *(const h8*)(uh + p * 32 +  0);                              \
        h8 u1_ = *(const h8*)(uh + p * 32 +  8);                              \
        h8 u2_ = *(const h8*)(uh + p * 32 + 16);                              \
        h8 u3_ = *(const h8*)(uh + p * 32 + 24);                              \
        DOT8(c0_, w2q0, u0_) DOT8(c1_, w2q1, u1_)                             \
        DOT8(c2_, w2q2, u2_) DOT8(c3_, w2q3, u3_)                             \
    }                                                                         \
    float cs_ = (c0_ + c1_) + (c2_ + c3_);                                    \
    KOUT = dppadd<0xB1>(cs_) + b2r;                                           \
} while (0)

// ---- prep: f16 GRU weights in [chunk][thread] coalesced layout ----
// WHx: 24576 h8. id = g*8192 + q*512 + t ; holds W_hh[j+256g][p*128+q*8 ..+8]
// WIx:  6144 h8. id = g*2048 + q*512 + t ; holds W_ih[j+256g][p*32+q*8 ..+8]
//                (cols >= 54 zero-padded), j=t>>1, p=t&1.
__global__ __launch_bounds__(256)
void prep_kernel(const float* __restrict__ W_ih, const float* __restrict__ W_hh,
                 h8* __restrict__ WHx, h8* __restrict__ WIx)
{
    const int id = blockIdx.x * 256 + threadIdx.x;
    if (id < 24576) {
        const int g = id >> 13, rem = id & 8191;
        const int q = rem >> 9, t = rem & 511;
        const int j = t >> 1, p = t & 1;
        const float* src = W_hh + (size_t)(j + 256 * g) * HDIM + p * 128 + q * 8;
        h8 v;
        #pragma unroll
        for (int e = 0; e < 8; ++e) v[e] = (_Float16)src[e];
        WHx[id] = v;
    } else if (id < 24576 + 6144) {
        const int id2 = id - 24576;
        const int g = id2 >> 11, rem = id2 & 2047;
        const int q = rem >> 9, t = rem & 511;
        const int j = t >> 1, p = t & 1;
        h8 v;
        #pragma unroll
        for (int e = 0; e < 8; ++e) {
            const int col = p * 32 + q * 8 + e;
            v[e] = (col < DIN) ? (_Float16)W_ih[(size_t)(j + 256 * g) * DIN + col]
                               : (_Float16)0.0f;
        }
        WIx[id2] = v;
    }
}

__global__ void
__attribute__((amdgpu_flat_work_group_size(512, 512), amdgpu_waves_per_eu(4, 4)))
odegru_kernel(const float* __restrict__ x,
              const float* __restrict__ tvec,
              const float* __restrict__ b_ih,
              const float* __restrict__ b_hh,
              const float* __restrict__ W1,
              const float* __restrict__ b1,
              const float* __restrict__ W2,
              const float* __restrict__ b2,
              const h8* __restrict__ WHx,
              const h8* __restrict__ WIx,
              float* __restrict__ out)
{
    const int t  = threadIdx.x;     // 0..511
    const int b  = blockIdx.x;      // batch row
    const int j  = t >> 1;          // element 0..255
    const int p  = t & 1;           // pair half
    const int i1 = t >> 3;          // drift stage1 output 0..63
    const int k8 = t & 7;           // stage1 k-chunk

    __shared__ __align__(16) _Float16 yA[HDIM];   // ping-pong y buffers
    __shared__ __align__(16) _Float16 yB[HDIM];
    __shared__ __align__(16) _Float16 uh[DH];
    __shared__ __align__(16) _Float16 xh[64];

    // Drift weights -> 8 named h8 vars (32 VGPRs).
    h8 w1m0, w1m1, w1m2, w1m3, w2q0, w2q1, w2q2, w2q3;
    {
        const float* base = W1 + (size_t)i1 * HDIM + k8 * 8;
        h8 v;
        #pragma unroll
        for (int e = 0; e < 8; ++e) v[e] = (_Float16)base[e +   0]; w1m0 = v;
        #pragma unroll
        for (int e = 0; e < 8; ++e) v[e] = (_Float16)base[e +  64]; w1m1 = v;
        #pragma unroll
        for (int e = 0; e < 8; ++e) v[e] = (_Float16)base[e + 128]; w1m2 = v;
        #pragma unroll
        for (int e = 0; e < 8; ++e) v[e] = (_Float16)base[e + 192]; w1m3 = v;
    }
    {
        const float* base = W2 + (size_t)j * DH + p * 32;
        h8 v;
        #pragma unroll
        for (int e = 0; e < 8; ++e) v[e] = (_Float16)base[e +  0]; w2q0 = v;
        #pragma unroll
        for (int e = 0; e < 8; ++e) v[e] = (_Float16)base[e +  8]; w2q1 = v;
        #pragma unroll
        for (int e = 0; e < 8; ++e) v[e] = (_Float16)base[e + 16]; w2q2 = v;
        #pragma unroll
        for (int e = 0; e < 8; ++e) v[e] = (_Float16)base[e + 24]; w2q3 = v;
    }

    const float b1r  = b1[i1];
    const float b2r  = b2[j];
    const float bihr = b_ih[j], bihz = b_ih[j + HDIM], bihn = b_ih[j + 2 * HDIM];
    const float bhhr = b_hh[j], bhhz = b_hh[j + HDIM], bhhn = b_hh[j + 2 * HDIM];

    const h8* __restrict__ WIr = WIx + t;
    const h8* __restrict__ WIz = WIx +  2048 + t;
    const h8* __restrict__ WIn = WIx +  4096 + t;
    const h8* __restrict__ WHr = WHx + t;
    const h8* __restrict__ WHz = WHx +  8192 + t;
    const h8* __restrict__ WHn = WHx + 16384 + t;

    float h = 0.0f;

    for (int i = 0; i < SEQ; ++i) {
        const int s = SEQ - 1 - i;

        if (t < 64)
            xh[t] = (t < DIN) ? (_Float16)x[((size_t)s * BATCH + b) * DIN + t]
                              : (_Float16)0.0f;
        if (p == 0) yA[j] = (_Float16)h;
        __syncthreads();

        // ---- GRU ih: 12 loads batched, then dots ----
        float xr = 0.f, xz = 0.f, xn = 0.f;
        {
            h8 ir0 = WIr[0], ir1 = WIr[512], ir2 = WIr[1024], ir3 = WIr[1536];
            h8 iz0 = WIz[0], iz1 = WIz[512], iz2 = WIz[1024], iz3 = WIz[1536];
            h8 in0 = WIn[0], in1 = WIn[512], in2 = WIn[1024], in3 = WIn[1536];
            h8 xv0 = *(const h8*)(xh + p * 32 +  0);
            h8 xv1 = *(const h8*)(xh + p * 32 +  8);
            h8 xv2 = *(const h8*)(xh + p * 32 + 16);
            h8 xv3 = *(const h8*)(xh + p * 32 + 24);
            DOT8(xr, ir0, xv0) DOT8(xr, ir1, xv1) DOT8(xr, ir2, xv2) DOT8(xr, ir3, xv3)
            DOT8(xz, iz0, xv0) DOT8(xz, iz1, xv1) DOT8(xz, iz2, xv2) DOT8(xz, iz3, xv3)
            DOT8(xn, in0, xv0) DOT8(xn, in1, xv1) DOT8(xn, in2, xv2) DOT8(xn, in3, xv3)
        }

        // ---- GRU hh: depth-2 software-pipelined tile prefetch ----
        float hr0 = 0.f, hz0 = 0.f, hn0 = 0.f;
        float hr1 = 0.f, hz1 = 0.f, hn1 = 0.f;
        {
            h8 cr0 = WHr[0],   cz0 = WHz[0],   cn0 = WHn[0];
            h8 cr1 = WHr[512], cz1 = WHz[512], cn1 = WHn[512];
            #pragma unroll
            for (int q = 0; q < 16; q += 2) {
                h8 nr0, nz0, nn0, nr1, nz1, nn1;
                if (q + 2 < 16) {
                    nr0 = WHr[(q+2)*512]; nz0 = WHz[(q+2)*512]; nn0 = WHn[(q+2)*512];
                    nr1 = WHr[(q+3)*512]; nz1 = WHz[(q+3)*512]; nn1 = WHn[(q+3)*512];
                } else { nr0=cr0; nz0=cz0; nn0=cn0; nr1=cr1; nz1=cz1; nn1=cn1; }
                h8 yv0 = *(const h8*)(yA + p * 128 + q * 8);
                h8 yv1 = *(const h8*)(yA + p * 128 + (q + 1) * 8);
                DOT8(hr0, cr0, yv0) DOT8(hz0, cz0, yv0) DOT8(hn0, cn0, yv0)
                DOT8(hr1, cr1, yv1) DOT8(hz1, cz1, yv1) DOT8(hn1, cn1, yv1)
                cr0 = nr0; cz0 = nz0; cn0 = nn0; cr1 = nr1; cz1 = nz1; cn1 = nn1;
            }
        }
        float Rp = dppadd<0xB1>(xr + hr0 + hr1);
        float Zp = dppadd<0xB1>(xz + hz0 + hz1);
        float Ip = dppadd<0xB1>(xn);
        float Hp = dppadd<0xB1>(hn0 + hn1);
        float r_g = fast_sigmoid(Rp + bihr + bhhr);
        float z_g = fast_sigmoid(Zp + bihz + bhhz);
        float n_g = fast_tanh(Ip + bihn + r_g * (Hp + bhhn));
        h = n_g + z_g * (h - n_g);
        // no barrier: drift1 writes yB; yA readers protected by drift1's B1/B2

        // ---- ODE integrate: single dopri5 step, ping-pong y buffers ----
        const float t0v = tvec[s];
        const float t1v = (s > 0) ? tvec[s - 1] : tvec[0];
        const float dt  = (t1v - t0v);

        if (dt != 0.0f) {   // block-uniform
            float k1, k2, k3, k4, k5, k6;
            DRIFT(yB, h, k1);
            DRIFT(yA, fmaf(dt * 0.2f, k1, h), k2);
            DRIFT(yB, h + dt * (0.075f * k1 + 0.225f * k2), k3);
            DRIFT(yA, h + dt * ((44.0f/45.0f) * k1 + (-56.0f/15.0f) * k2
                              + (32.0f/9.0f)  * k3), k4);
            DRIFT(yB, h + dt * ((19372.0f/6561.0f) * k1 + (-25360.0f/2187.0f) * k2
                              + (64448.0f/6561.0f) * k3 + (-212.0f/729.0f)   * k4), k5);
            DRIFT(yA, h + dt * ((9017.0f/3168.0f)  * k1 + (-355.0f/33.0f)    * k2
                              + (46732.0f/5247.0f) * k3 + (49.0f/176.0f)     * k4
                              + (-5103.0f/18656.0f)* k5), k6);
            h = h + dt * ((35.0f/384.0f)    * k1 + (500.0f/1113.0f)  * k3
                        + (125.0f/192.0f)   * k4 + (-2187.0f/6784.0f) * k5
                        + (11.0f/84.0f)     * k6);
        } else {
            __syncthreads();   // degenerate dt: keep next-step writes ordered
        }

        if (p == 0) out[((size_t)s * BATCH + b) * HDIM + j] = h;
        // no bottom barrier: next top writes are WAR-safe (>=1 barrier gap)
    }
}

extern "C" void kernel_launch(void* const* d_in, const int* in_sizes, int n_in,
                              void* d_out, int out_size, void* d_ws, size_t ws_size,
                              hipStream_t stream) {
    const float* x    = (const float*)d_in[0];
    const float* tvec = (const float*)d_in[1];
    const float* W_ih = (const float*)d_in[2];
    const float* W_hh = (const float*)d_in[3];
    const float* b_ih = (const float*)d_in[4];
    const float* b_hh = (const float*)d_in[5];
    const float* W1   = (const float*)d_in[6];
    const float* b1   = (const float*)d_in[7];
    const float* W2   = (const float*)d_in[8];
    const float* b2   = (const float*)d_in[9];
    float* out = (float*)d_out;

    h8* WHx = (h8*)d_ws;                                   // 24576*16 = 393216 B
    h8* WIx = (h8*)((char*)d_ws + 24576 * 16);             //  6144*16 =  98304 B

    hipLaunchKernelGGL(prep_kernel, dim3(120), dim3(256), 0, stream,
                       W_ih, W_hh, WHx, WIx);
    hipLaunchKernelGGL(odegru_kernel, dim3(BATCH), dim3(512), 0, stream,
                       x, tvec, b_ih, b_hh, W1, b1, W2, b2, WHx, WIx, out);
}

// Round 9
// 3085.977 us; speedup vs baseline: 6.0544x; 6.0544x over previous
//
#include <hip/hip_runtime.h>

// ODE-GRU on MI355X, round 9.
// EXACT round-7 structure (512x512, pair-split f16 dot2, 8-way drift stage1,
// single dopri5 step, f16 GRU weights streamed from d_ws, round-7 load
// placement and barrier structure). Round 8's batched/prefetched loads blew
// the 64-VGPR budget -> scratch re-reads -> 42 GB HBM stream; reverted.
// Kept from round 8 (register-neutral, no memory):
//  1. Cross-lane reductions via DPP v_add (quad_perm 0xB1 lane^1,
//     quad_perm 0x4E lane^2, row_half_mirror 0x141 for the 8-lane finish)
//     instead of __shfl_xor's ds_swizzle LDS round-trips.
//  2. tanh computed by all lanes (only the uh ds_write masked).

#define SEQ   256
#define BATCH 512
#define DIN   54
#define HDIM  256
#define DH    64

typedef _Float16 h2 __attribute__((ext_vector_type(2)));
typedef _Float16 h8 __attribute__((ext_vector_type(8)));

#define PX(v, p) __builtin_shufflevector((v), (v), 2*(p), 2*(p)+1)

#if defined(__has_builtin)
#  if __has_builtin(__builtin_amdgcn_fdot2)
#    define FDOT2(a, b, c) __builtin_amdgcn_fdot2((a), (b), (c), false)
#  endif
#endif
#ifndef FDOT2
#  define FDOT2(a, b, c) fmaf((float)(a)[0], (float)(b)[0], \
                         fmaf((float)(a)[1], (float)(b)[1], (c)))
#endif

__device__ __forceinline__ float rcp_f(float x) { return __builtin_amdgcn_rcpf(x); }

__device__ __forceinline__ float fast_tanh(float x) {
    x = fminf(15.0f, fmaxf(-15.0f, x));
    float e = __expf(2.0f * x);
    return 1.0f - 2.0f * rcp_f(e + 1.0f);
}
__device__ __forceinline__ float fast_sigmoid(float x) {
    x = fminf(30.0f, fmaxf(-30.0f, x));
    return rcp_f(1.0f + __expf(-x));
}

// x + dpp_permute(x): cross-lane add at VALU latency (no LDS round-trip).
// 0xB1 = quad_perm [1,0,3,2] (lane^1). 0x4E = quad_perm [2,3,0,1] (lane^2).
// 0x141 = row_half_mirror (mirror within 8 lanes) -- valid as the 8-lane
// finisher because after xor1+xor2 the value is quad-uniform, and the mirror
// always lands in the opposite quad of the same 8-lane group.
template <int CTRL>
__device__ __forceinline__ float dppadd(float x) {
    return x + __int_as_float(
        __builtin_amdgcn_mov_dpp(__float_as_int(x), CTRL, 0xF, 0xF, true));
}

// 4 dot2: accumulate h8 W . h8 Y into A
#define DOT8(A, W, Y) { \
    A = FDOT2(PX(W,0), PX(Y,0), A); A = FDOT2(PX(W,1), PX(Y,1), A); \
    A = FDOT2(PX(W,2), PX(Y,2), A); A = FDOT2(PX(W,3), PX(Y,3), A); }

// Drift eval: per-thread y (element j, replicated on pair) -> per-thread k.
// Stage1: 8-lane group (same i1=t>>3) covers k-chunks {k8*8 + m*64}, m=0..3
// (interleaved -> 8 distinct LDS addrs, conflict-free, 8-lane broadcast);
// DPP xor1/xor2/mirror8 completes the 256-dot. Stage2: pair halves over uh
// (broadcast reads), DPP xor1 completes. 2 barriers per drift.
#define DRIFT(Y_EXPR, KOUT) do {                                              \
    if (p == 0) yh[j] = (_Float16)(Y_EXPR);                                   \
    __syncthreads();                                                          \
    float a0_ = 0.f, a1_ = 0.f, a2_ = 0.f, a3_ = 0.f;                         \
    {                                                                         \
        h8 v0_ = *(const h8*)(yh + k8 * 8 +   0);                             \
        h8 v1_ = *(const h8*)(yh + k8 * 8 +  64);                             \
        h8 v2_ = *(const h8*)(yh + k8 * 8 + 128);                             \
        h8 v3_ = *(const h8*)(yh + k8 * 8 + 192);                             \
        DOT8(a0_, w1m0, v0_) DOT8(a1_, w1m1, v1_)                             \
        DOT8(a2_, w1m2, v2_) DOT8(a3_, w1m3, v3_)                             \
    }                                                                         \
    float as_ = (a0_ + a1_) + (a2_ + a3_);                                    \
    as_ = dppadd<0xB1>(as_);                                                  \
    as_ = dppadd<0x4E>(as_);                                                  \
    as_ = dppadd<0x141>(as_);                                                 \
    float uu_ = fast_tanh(as_ + b1r);                                         \
    if (k8 == 0) uh[i1] = (_Float16)uu_;                                      \
    __syncthreads();                                                          \
    float c0_ = 0.f, c1_ = 0.f, c2_ = 0.f, c3_ = 0.f;                         \
    {                                                                         \
        h8 u0_ = *(const h8*)(uh + p * 32 +  0);                              \
        h8 u1_ = *(const h8*)(uh + p * 32 +  8);                              \
        h8 u2_ = *(const h8*)(uh + p * 32 + 16);                              \
        h8 u3_ = *(const h8*)(uh + p * 32 + 24);                              \
        DOT8(c0_, w2q0, u0_) DOT8(c1_, w2q1, u1_)                             \
        DOT8(c2_, w2q2, u2_) DOT8(c3_, w2q3, u3_)                             \
    }                                                                         \
    float cs_ = (c0_ + c1_) + (c2_ + c3_);                                    \
    KOUT = dppadd<0xB1>(cs_) + b2r;                                           \
} while (0)

// ---- prep: f16 GRU weights in [chunk][thread] coalesced layout ----
// WHx: 24576 h8. id = g*8192 + q*512 + t ; holds W_hh[j+256g][p*128+q*8 ..+8]
// WIx:  6144 h8. id = g*2048 + q*512 + t ; holds W_ih[j+256g][p*32+q*8 ..+8]
//                (cols >= 54 zero-padded), j=t>>1, p=t&1.
__global__ __launch_bounds__(256)
void prep_kernel(const float* __restrict__ W_ih, const float* __restrict__ W_hh,
                 h8* __restrict__ WHx, h8* __restrict__ WIx)
{
    const int id = blockIdx.x * 256 + threadIdx.x;
    if (id < 24576) {
        const int g = id >> 13, rem = id & 8191;
        const int q = rem >> 9, t = rem & 511;
        const int j = t >> 1, p = t & 1;
        const float* src = W_hh + (size_t)(j + 256 * g) * HDIM + p * 128 + q * 8;
        h8 v;
        #pragma unroll
        for (int e = 0; e < 8; ++e) v[e] = (_Float16)src[e];
        WHx[id] = v;
    } else if (id < 24576 + 6144) {
        const int id2 = id - 24576;
        const int g = id2 >> 11, rem = id2 & 2047;
        const int q = rem >> 9, t = rem & 511;
        const int j = t >> 1, p = t & 1;
        h8 v;
        #pragma unroll
        for (int e = 0; e < 8; ++e) {
            const int col = p * 32 + q * 8 + e;
            v[e] = (col < DIN) ? (_Float16)W_ih[(size_t)(j + 256 * g) * DIN + col]
                               : (_Float16)0.0f;
        }
        WIx[id2] = v;
    }
}

__global__ void
__attribute__((amdgpu_flat_work_group_size(512, 512), amdgpu_waves_per_eu(4, 4)))
odegru_kernel(const float* __restrict__ x,
              const float* __restrict__ tvec,
              const float* __restrict__ b_ih,
              const float* __restrict__ b_hh,
              const float* __restrict__ W1,
              const float* __restrict__ b1,
              const float* __restrict__ W2,
              const float* __restrict__ b2,
              const h8* __restrict__ WHx,
              const h8* __restrict__ WIx,
              float* __restrict__ out)
{
    const int t  = threadIdx.x;     // 0..511
    const int b  = blockIdx.x;      // batch row
    const int j  = t >> 1;          // element 0..255
    const int p  = t & 1;           // pair half
    const int i1 = t >> 3;          // drift stage1 output 0..63
    const int k8 = t & 7;           // stage1 k-chunk

    __shared__ __align__(16) _Float16 yh[HDIM];
    __shared__ __align__(16) _Float16 uh[DH];
    __shared__ __align__(16) _Float16 xh[64];

    // Drift weights -> 8 named h8 vars (32 VGPRs).
    // w1m{m}: W1[i1][k8*8 + m*64 ..+8] ; w2q{q}: W2[j][p*32 + q*8 ..+8]
    h8 w1m0, w1m1, w1m2, w1m3, w2q0, w2q1, w2q2, w2q3;
    {
        const float* base = W1 + (size_t)i1 * HDIM + k8 * 8;
        h8 v;
        #pragma unroll
        for (int e = 0; e < 8; ++e) v[e] = (_Float16)base[e +   0]; w1m0 = v;
        #pragma unroll
        for (int e = 0; e < 8; ++e) v[e] = (_Float16)base[e +  64]; w1m1 = v;
        #pragma unroll
        for (int e = 0; e < 8; ++e) v[e] = (_Float16)base[e + 128]; w1m2 = v;
        #pragma unroll
        for (int e = 0; e < 8; ++e) v[e] = (_Float16)base[e + 192]; w1m3 = v;
    }
    {
        const float* base = W2 + (size_t)j * DH + p * 32;
        h8 v;
        #pragma unroll
        for (int e = 0; e < 8; ++e) v[e] = (_Float16)base[e +  0]; w2q0 = v;
        #pragma unroll
        for (int e = 0; e < 8; ++e) v[e] = (_Float16)base[e +  8]; w2q1 = v;
        #pragma unroll
        for (int e = 0; e < 8; ++e) v[e] = (_Float16)base[e + 16]; w2q2 = v;
        #pragma unroll
        for (int e = 0; e < 8; ++e) v[e] = (_Float16)base[e + 24]; w2q3 = v;
    }

    const float b1r  = b1[i1];
    const float b2r  = b2[j];
    const float bihr = b_ih[j], bihz = b_ih[j + HDIM], bihn = b_ih[j + 2 * HDIM];
    const float bhhr = b_hh[j], bhhz = b_hh[j + HDIM], bhhn = b_hh[j + 2 * HDIM];

    float h = 0.0f;

    for (int i = 0; i < SEQ; ++i) {
        const int s = SEQ - 1 - i;

        if (t < 64)
            xh[t] = (t < DIN) ? (_Float16)x[((size_t)s * BATCH + b) * DIN + t]
                              : (_Float16)0.0f;
        if (p == 0) yh[j] = (_Float16)h;
        __syncthreads();

        // ---- GRU: pair-split dots, f32 accumulate (round-7 load placement) ----
        float xr = 0.f, xz = 0.f, xn = 0.f;                 // ih partials
        #pragma unroll
        for (int q = 0; q < 4; ++q) {
            h8 xv = *(const h8*)(xh + p * 32 + q * 8);
            h8 wr = WIx[(0 * 4 + q) * 512 + t];
            h8 wz = WIx[(1 * 4 + q) * 512 + t];
            h8 wn = WIx[(2 * 4 + q) * 512 + t];
            DOT8(xr, wr, xv) DOT8(xz, wz, xv) DOT8(xn, wn, xv)
        }
        float hr0 = 0.f, hz0 = 0.f, hn0 = 0.f;              // hh partials
        float hr1 = 0.f, hz1 = 0.f, hn1 = 0.f;
        #pragma unroll 2
        for (int q = 0; q < 16; q += 2) {
            {
                h8 yv = *(const h8*)(yh + p * 128 + q * 8);
                h8 wr = WHx[(0 * 16 + q) * 512 + t];
                h8 wz = WHx[(1 * 16 + q) * 512 + t];
                h8 wn = WHx[(2 * 16 + q) * 512 + t];
                DOT8(hr0, wr, yv) DOT8(hz0, wz, yv) DOT8(hn0, wn, yv)
            }
            {
                h8 yv = *(const h8*)(yh + p * 128 + (q + 1) * 8);
                h8 wr = WHx[(0 * 16 + q + 1) * 512 + t];
                h8 wz = WHx[(1 * 16 + q + 1) * 512 + t];
                h8 wn = WHx[(2 * 16 + q + 1) * 512 + t];
                DOT8(hr1, wr, yv) DOT8(hz1, wz, yv) DOT8(hn1, wn, yv)
            }
        }
        float Rp = dppadd<0xB1>(xr + hr0 + hr1);
        float Zp = dppadd<0xB1>(xz + hz0 + hz1);
        float Ip = dppadd<0xB1>(xn);
        float Hp = dppadd<0xB1>(hn0 + hn1);
        float r_g = fast_sigmoid(Rp + bihr + bhhr);
        float z_g = fast_sigmoid(Zp + bihz + bhhz);
        float n_g = fast_tanh(Ip + bihn + r_g * (Hp + bhhn));
        h = n_g + z_g * (h - n_g);
        __syncthreads();   // all yh reads done before drift overwrites yh

        // ---- ODE integrate: single dopri5 step over the whole interval ----
        const float t0v = tvec[s];
        const float t1v = (s > 0) ? tvec[s - 1] : tvec[0];
        const float dt  = (t1v - t0v);

        if (dt != 0.0f) {   // block-uniform; dt==0 only at s==0 (exact skip)
            float k1, k2, k3, k4, k5, k6;
            DRIFT(h, k1);
            DRIFT(fmaf(dt * 0.2f, k1, h), k2);
            DRIFT(h + dt * (0.075f * k1 + 0.225f * k2), k3);
            DRIFT(h + dt * ((44.0f/45.0f) * k1 + (-56.0f/15.0f) * k2
                          + (32.0f/9.0f)  * k3), k4);
            DRIFT(h + dt * ((19372.0f/6561.0f) * k1 + (-25360.0f/2187.0f) * k2
                          + (64448.0f/6561.0f) * k3 + (-212.0f/729.0f)   * k4), k5);
            DRIFT(h + dt * ((9017.0f/3168.0f)  * k1 + (-355.0f/33.0f)    * k2
                          + (46732.0f/5247.0f) * k3 + (49.0f/176.0f)     * k4
                          + (-5103.0f/18656.0f)* k5), k6);
            h = h + dt * ((35.0f/384.0f)    * k1 + (500.0f/1113.0f)  * k3
                        + (125.0f/192.0f)   * k4 + (-2187.0f/6784.0f) * k5
                        + (11.0f/84.0f)     * k6);
        }

        if (p == 0) out[((size_t)s * BATCH + b) * HDIM + j] = h;
        __syncthreads();   // protect next step's xh/yh writes
    }
}

extern "C" void kernel_launch(void* const* d_in, const int* in_sizes, int n_in,
                              void* d_out, int out_size, void* d_ws, size_t ws_size,
                              hipStream_t stream) {
    const float* x    = (const float*)d_in[0];
    const float* tvec = (const float*)d_in[1];
    const float* W_ih = (const float*)d_in[2];
    const float* W_hh = (const float*)d_in[3];
    const float* b_ih = (const float*)d_in[4];
    const float* b_hh = (const float*)d_in[5];
    const float* W1   = (const float*)d_in[6];
    const float* b1   = (const float*)d_in[7];
    const float* W2   = (const float*)d_in[8];
    const float* b2   = (const float*)d_in[9];
    float* out = (float*)d_out;

    h8* WHx = (h8*)d_ws;                                   // 24576*16 = 393216 B
    h8* WIx = (h8*)((char*)d_ws + 24576 * 16);             //  6144*16 =  98304 B

    hipLaunchKernelGGL(prep_kernel, dim3(120), dim3(256), 0, stream,
                       W_ih, W_hh, WHx, WIx);
    hipLaunchKernelGGL(odegru_kernel, dim3(BATCH), dim3(512), 0, stream,
                       x, tvec, b_ih, b_hh, W1, b1, W2, b2, WHx, WIx, out);
}